// Round 13
// baseline (248.485 us; speedup 1.0000x reference)
//
#include <hip/hip_runtime.h>
#include <hip/hip_fp16.h>

typedef _Float16 half8 __attribute__((ext_vector_type(8)));
typedef float floatx4 __attribute__((ext_vector_type(4)));
typedef unsigned int uintx4 __attribute__((ext_vector_type(4)));

// ---------------- helpers ----------------

__device__ __forceinline__ void unpack8(uint4 v, float* f) {
    const __half2* hp = (const __half2*)&v;
    float2 a = __half22float2(hp[0]);
    float2 b = __half22float2(hp[1]);
    float2 c = __half22float2(hp[2]);
    float2 d = __half22float2(hp[3]);
    f[0] = a.x; f[1] = a.y; f[2] = b.x; f[3] = b.y;
    f[4] = c.x; f[5] = c.y; f[6] = d.x; f[7] = d.y;
}

__device__ __forceinline__ uint4 pack8(const float* f) {
    __half2 h0 = __floats2half2_rn(f[0], f[1]);
    __half2 h1 = __floats2half2_rn(f[2], f[3]);
    __half2 h2 = __floats2half2_rn(f[4], f[5]);
    __half2 h3 = __floats2half2_rn(f[6], f[7]);
    uint4 v;
    v.x = *(const unsigned int*)&h0;
    v.y = *(const unsigned int*)&h1;
    v.z = *(const unsigned int*)&h2;
    v.w = *(const unsigned int*)&h3;
    return v;
}

__device__ __forceinline__ void nt_store16(void* p, uint4 v) {
    uintx4 e;
    e.x = v.x; e.y = v.y; e.z = v.z; e.w = v.w;
    __builtin_nontemporal_store(e, (uintx4*)p);
}

__device__ __forceinline__ void nt_store16f(void* p, float4 v) {
    floatx4 e;
    e.x = v.x; e.y = v.y; e.z = v.z; e.w = v.w;
    __builtin_nontemporal_store(e, (floatx4*)p);
}

// ---------------- setup: W pack + zero + edge uint16 pack (fused) ----------------

__global__ void k_setup(const float* __restrict__ W1, const float* __restrict__ W2,
                        const float* __restrict__ W3, __half* __restrict__ Wt1,
                        __half* __restrict__ Wt2, __half* __restrict__ Wt3,
                        int* __restrict__ zp, int zn,
                        const int* __restrict__ ei, unsigned short* __restrict__ e16,
                        int E) {
    const int PW = 2 * 128 * 128 + 48 * 128;
    int i = blockIdx.x * 256 + threadIdx.x;
    if (i < 128 * 128) {
        int n = i >> 7, k = i & 127;
        Wt1[i] = __float2half(W1[(size_t)k * 128 + n]);
    } else if (i < 2 * 128 * 128) {
        int j = i - 128 * 128;
        int n = j >> 7, k = j & 127;
        Wt2[j] = __float2half(W2[(size_t)k * 128 + n]);
    } else if (i < PW) {
        int j = i - 2 * 128 * 128;
        int n = j >> 7, k = j & 127;
        Wt3[j] = (n < 40) ? __float2half(W3[(size_t)k * 40 + n]) : __half(0.f);
    } else if (i < PW + zn) {
        zp[i - PW] = 0;
    } else {
        int j = i - PW - zn;
        if (j < E) e16[j] = (unsigned short)ei[E + j];            // dst16
        else if (j < 2 * E) e16[j] = (unsigned short)ei[j - E];   // src16
    }
}

// ---------------- CSR build (counting sort, XCD-range-partitioned, uint16) ----------------

__global__ void k_deg_xcd(const unsigned short* __restrict__ dst, int* __restrict__ deg,
                          int E, int rs) {
    int lo = (blockIdx.x & 7) * rs;
    int i = (blockIdx.x >> 3) * 256 + threadIdx.x;
    if (i < E) {
        int d = dst[i];
        if (d >= lo && d < lo + rs) atomicAdd(&deg[d], 1);
    }
}

__global__ void k_place_xcd(const unsigned short* __restrict__ src,
                            const unsigned short* __restrict__ dst,
                            int* __restrict__ cursor, unsigned short* __restrict__ sidx,
                            int E, int rs) {
    int lo = (blockIdx.x & 7) * rs;
    int i = (blockIdx.x >> 3) * 256 + threadIdx.x;
    if (i < E) {
        int d = dst[i];
        if (d >= lo && d < lo + rs) {
            int pos = atomicAdd(&cursor[d], 1);
            sidx[pos] = src[i];
        }
    }
}

__global__ __launch_bounds__(256) void k_chunkscan(const int* __restrict__ deg,
                                                   int* __restrict__ bsum, int n) {
    __shared__ int ls[256];
    int t = threadIdx.x;
    int s = 0;
    int base = t * 256;
    for (int k = 0; k < 256; ++k) {
        int idx = base + k;
        if (idx < n) s += deg[idx];
    }
    ls[t] = s;
    __syncthreads();
    for (int off = 1; off < 256; off <<= 1) {
        int v = t >= off ? ls[t - off] : 0;
        __syncthreads();
        ls[t] += v;
        __syncthreads();
    }
    bsum[t] = ls[t] - s;  // exclusive
}

__global__ void k_scanchunk(const int* __restrict__ cnt, const int* __restrict__ bsum,
                            int* __restrict__ row_ptr, int* __restrict__ cursor,
                            float* __restrict__ dinv, int n, int E) {
    __shared__ int ls[256];
    int i = blockIdx.x * 256 + threadIdx.x;
    int v = i < n ? cnt[i] : 0;
    ls[threadIdx.x] = v;
    __syncthreads();
    for (int off = 1; off < 256; off <<= 1) {
        int t = threadIdx.x >= off ? ls[threadIdx.x - off] : 0;
        __syncthreads();
        ls[threadIdx.x] += t;
        __syncthreads();
    }
    if (i < n) {
        int ex = ls[threadIdx.x] - v + bsum[blockIdx.x];
        row_ptr[i] = ex;
        cursor[i] = ex;
        dinv[i] = v > 0 ? rsqrtf((float)v) : 0.f;
    }
    if (i == n - 1) row_ptr[n] = E;
}

// ---------------- MFMA GEMM v4 (stripe-aware, nt stores to stripes) ----------------

template <int CT, int STRIDE, int VALID, int AMODE, int CSPLIT, int ASTRIPE, int CSTRIPE>
__global__ __launch_bounds__(256) void k_gemm_mfma(const void* __restrict__ Ap,
                                                   const __half* __restrict__ Wt,
                                                   const float* __restrict__ sums32,
                                                   const float* __restrict__ sumsq32,
                                                   const float* __restrict__ g,
                                                   const float* __restrict__ beta,
                                                   const float* __restrict__ dinv,
                                                   __half* __restrict__ C, int nrows) {
    constexpr int CW = CT * 16;
    __shared__ char lw[CT * 16 * 256];
    __shared__ float lsc[128], lsh[128];
    const int rowblk = (CSPLIT == 2) ? (blockIdx.x >> 1) : blockIdx.x;
    const int colblk = (CSPLIT == 2) ? (blockIdx.x & 1) : 0;

    const int lane = threadIdx.x & 63;
    const int wid = threadIdx.x >> 6;
    const int l15 = lane & 15;
    const int lg = lane >> 4;
    const int rowbase = rowblk * 128 + wid * 32;

    // ---- phase 0: issue raw A loads (latency hides under W staging) ----
    uint4 raw16[2][4];
    float4 raw32[2][4][2];
#pragma unroll
    for (int r = 0; r < 2; ++r) {
        int row = rowbase + r * 16 + l15;
        bool ok = row < nrows;
#pragma unroll
        for (int kk = 0; kk < 4; ++kk) {
            const int c0 = kk * 32 + lg * 8;
            if (AMODE == 0) {
                const float* a = (const float*)Ap + (size_t)row * 128 + c0;
                raw32[r][kk][0] = ok ? *(const float4*)a : make_float4(0.f, 0.f, 0.f, 0.f);
                raw32[r][kk][1] = ok ? *(const float4*)(a + 4) : make_float4(0.f, 0.f, 0.f, 0.f);
            } else if (ASTRIPE) {
                const __half* a = (const __half*)Ap + ((size_t)kk * nrows + row) * 32 + lg * 8;
                raw16[r][kk] = ok ? *(const uint4*)a : make_uint4(0, 0, 0, 0);
            } else {
                raw16[r][kk] = ok ? *(const uint4*)((const __half*)Ap + (size_t)row * 128 + c0)
                                  : make_uint4(0, 0, 0, 0);
            }
        }
    }

    // ---- phase 1: W stage + BN coeffs ----
    const int nu4 = CT * 16 * 16;
    for (int i = threadIdx.x; i < nu4; i += 256) {
        int row = i >> 4, k8 = i & 15;
        uint4 v = ((const uint4*)Wt)[(colblk * CW + row) * 16 + k8];
        *(uint4*)(lw + ((row * 256 + k8 * 16) ^ ((row & 7) << 4))) = v;
    }
    if (AMODE == 1 && threadIdx.x < 128) {
        int c = threadIdx.x;
        float s = 0.f, q = 0.f;
        for (int k2 = 0; k2 < 32; ++k2) {
            s += sums32[k2 * 128 + c];
            q += sumsq32[k2 * 128 + c];
        }
        float inv_n = 1.f / (float)nrows;
        float mu = s * inv_n;
        float var = q * inv_n - mu * mu;
        float rs = rsqrtf(var + 1e-5f);
        float sc = rs * g[c];
        lsc[c] = sc;
        lsh[c] = beta[c] - mu * sc;
    }
    __syncthreads();

    // ---- phase 2: convert/BN-apply A fragments ----
    half8 a2[2][4];
#pragma unroll
    for (int r = 0; r < 2; ++r) {
#pragma unroll
        for (int kk = 0; kk < 4; ++kk) {
            const int c0 = kk * 32 + lg * 8;
            half8 h;
            if (AMODE == 0) {
                float4 v0 = raw32[r][kk][0];
                float4 v1 = raw32[r][kk][1];
                h[0] = (_Float16)v0.x; h[1] = (_Float16)v0.y;
                h[2] = (_Float16)v0.z; h[3] = (_Float16)v0.w;
                h[4] = (_Float16)v1.x; h[5] = (_Float16)v1.y;
                h[6] = (_Float16)v1.z; h[7] = (_Float16)v1.w;
            } else {
                float f[8];
                unpack8(raw16[r][kk], f);
                float4 s0 = *(const float4*)&lsc[c0];
                float4 s1 = *(const float4*)&lsc[c0 + 4];
                float4 t0 = *(const float4*)&lsh[c0];
                float4 t1 = *(const float4*)&lsh[c0 + 4];
                h[0] = (_Float16)fmaxf(f[0] * s0.x + t0.x, 0.f);
                h[1] = (_Float16)fmaxf(f[1] * s0.y + t0.y, 0.f);
                h[2] = (_Float16)fmaxf(f[2] * s0.z + t0.z, 0.f);
                h[3] = (_Float16)fmaxf(f[3] * s0.w + t0.w, 0.f);
                h[4] = (_Float16)fmaxf(f[4] * s1.x + t1.x, 0.f);
                h[5] = (_Float16)fmaxf(f[5] * s1.y + t1.y, 0.f);
                h[6] = (_Float16)fmaxf(f[6] * s1.z + t1.z, 0.f);
                h[7] = (_Float16)fmaxf(f[7] * s1.w + t1.w, 0.f);
            }
            a2[r][kk] = h;
        }
    }

    floatx4 acc[2][CT];
#pragma unroll
    for (int r = 0; r < 2; ++r)
#pragma unroll
        for (int c = 0; c < CT; ++c) acc[r][c] = (floatx4){0.f, 0.f, 0.f, 0.f};

#pragma unroll
    for (int kk = 0; kk < 4; ++kk) {
#pragma unroll
        for (int c = 0; c < CT; ++c) {
            int wrow = c * 16 + l15;
            half8 bfrag = *(const half8*)(lw + ((wrow * 256 + kk * 64 + lg * 16) ^ ((wrow & 7) << 4)));
#pragma unroll
            for (int r = 0; r < 2; ++r)
                acc[r][c] = __builtin_amdgcn_mfma_f32_16x16x32_f16(a2[r][kk], bfrag, acc[r][c], 0, 0, 0);
        }
    }

    // ---- epilogue: LDS transpose [128][CW], coalesced stores ----
    __syncthreads();
    __half* ct = (__half*)lw;
#pragma unroll
    for (int r = 0; r < 2; ++r) {
        int lr0 = wid * 32 + r * 16 + lg * 4;
        float d4[4];
#pragma unroll
        for (int j = 0; j < 4; ++j) {
            int row = rowblk * 128 + lr0 + j;
            d4[j] = row < nrows ? dinv[row] : 0.f;
        }
#pragma unroll
        for (int c = 0; c < CT; ++c) {
            int col = c * 16 + l15;
#pragma unroll
            for (int j = 0; j < 4; ++j) {
                int lrow = lr0 + j;
                int cc = (CW == 64) ? (col ^ (((lrow >> 2) & 1) << 5)) : col;
                ct[lrow * CW + cc] = __float2half(acc[r][c][j] * d4[j]);
            }
        }
    }
    __syncthreads();
    constexpr int U = CW / 8;
    for (int i = threadIdx.x; i < 128 * U; i += 256) {
        int lrow = i / U, u = i % U;
        int row = rowblk * 128 + lrow;
        int col0 = u * 8;
        int g2 = colblk * CW + col0;
        if (row < nrows && (CSTRIPE || col0 < VALID)) {
            int cc = (CW == 64) ? (col0 ^ (((lrow >> 2) & 1) << 5)) : col0;
            uint4 v = *(const uint4*)&ct[lrow * CW + cc];
            if (CSTRIPE)
                nt_store16(&C[((size_t)(g2 >> 5) * nrows + row) * 32 + (g2 & 31)], v);
            else
                *(uint4*)(&C[(size_t)row * STRIDE + g2]) = v;
        }
    }
}

// ---------------- stripe aggregation + fused BN stats ----------------
// nt-load sidx (read-once stream), nt-store H4 (write-once) so the 3.2 MB
// gather stripe stays resident in the XCD-pair's L2.

__global__ __launch_bounds__(256) void k_agg32_stats(const __half* __restrict__ M4,
                                                     const int* __restrict__ rp,
                                                     const unsigned short* __restrict__ sidx,
                                                     const float* __restrict__ dinv,
                                                     __half* __restrict__ H4,
                                                     float* __restrict__ sums32,
                                                     float* __restrict__ sumsq32, int n) {
    int b = blockIdx.x;
    int pass = (b >> 1) & 3;
    int nodeblk = (b >> 3) * 2 + (b & 1);
    int tid = threadIdx.x;
    int d = nodeblk * 64 + (tid >> 2);
    int lane4 = tid & 3;
    const __half* Mp = M4 + (size_t)pass * n * 32;

    float acc[8] = {0.f, 0.f, 0.f, 0.f, 0.f, 0.f, 0.f, 0.f};
    if (d < n) {
        int beg = rp[d], end = rp[d + 1];
        int j = beg;
        for (; j + 4 <= end; j += 4) {
            int s0 = __builtin_nontemporal_load(&sidx[j]);
            int s1 = __builtin_nontemporal_load(&sidx[j + 1]);
            int s2 = __builtin_nontemporal_load(&sidx[j + 2]);
            int s3 = __builtin_nontemporal_load(&sidx[j + 3]);
            uint4 v0 = *(const uint4*)(Mp + (size_t)s0 * 32 + lane4 * 8);
            uint4 v1 = *(const uint4*)(Mp + (size_t)s1 * 32 + lane4 * 8);
            uint4 v2 = *(const uint4*)(Mp + (size_t)s2 * 32 + lane4 * 8);
            uint4 v3 = *(const uint4*)(Mp + (size_t)s3 * 32 + lane4 * 8);
            float f0[8], f1[8], f2[8], f3[8];
            unpack8(v0, f0); unpack8(v1, f1); unpack8(v2, f2); unpack8(v3, f3);
#pragma unroll
            for (int i = 0; i < 8; ++i)
                acc[i] += (f0[i] + f1[i]) + (f2[i] + f3[i]);
        }
        for (; j < end; ++j) {
            int s = __builtin_nontemporal_load(&sidx[j]);
            uint4 v = *(const uint4*)(Mp + (size_t)s * 32 + lane4 * 8);
            float f[8];
            unpack8(v, f);
#pragma unroll
            for (int i = 0; i < 8; ++i) acc[i] += f[i];
        }
        float sc = dinv[d];
#pragma unroll
        for (int i = 0; i < 8; ++i) acc[i] *= sc;
        uint4 pk = pack8(acc);
        nt_store16(H4 + (size_t)pass * n * 32 + (size_t)d * 32 + lane4 * 8, pk);
    }

    // per-pass column stats (cols pass*32 + lane4*8 + [0,8))
    float sq[8];
#pragma unroll
    for (int i = 0; i < 8; ++i) sq[i] = acc[i] * acc[i];
#pragma unroll
    for (int m = 4; m <= 32; m <<= 1) {
#pragma unroll
        for (int i = 0; i < 8; ++i) {
            acc[i] += __shfl_xor(acc[i], m);
            sq[i]  += __shfl_xor(sq[i], m);
        }
    }
    __shared__ float lsw[2][4][4][8];  // 1 KB
    int wid = tid >> 6, wl = tid & 63;
    if (wl < 4) {
#pragma unroll
        for (int i = 0; i < 8; ++i) {
            lsw[0][wid][wl][i] = acc[i];
            lsw[1][wid][wl][i] = sq[i];
        }
    }
    __syncthreads();
    if (tid < 32) {
        int lc = tid >> 3, e = tid & 7;
        float ss = 0.f, qq = 0.f;
#pragma unroll
        for (int w = 0; w < 4; ++w) {
            ss += lsw[0][w][lc][e];
            qq += lsw[1][w][lc][e];
        }
        int sh = (b & 31) * 128;
        int c = pass * 32 + tid;
        atomicAdd(&sums32[sh + c], ss);
        atomicAdd(&sumsq32[sh + c], qq);
    }
}

// ---------------- layer-3 aggregation (t3 row stride 64) ----------------

__global__ void k_agg40_f16(const __half* __restrict__ M,
                            const int* __restrict__ rp,
                            const unsigned short* __restrict__ sidx,
                            const float* __restrict__ dinv,
                            const float* __restrict__ b3,
                            float* __restrict__ out, int n) {
    int i = blockIdx.x * 256 + threadIdx.x;
    if (i >= n * 5) return;
    int d = i / 5, q = i % 5;
    int beg = rp[d], end = rp[d + 1];
    float acc[8] = {0.f, 0.f, 0.f, 0.f, 0.f, 0.f, 0.f, 0.f};
    int j = beg;
    for (; j + 4 <= end; j += 4) {
        int s0 = __builtin_nontemporal_load(&sidx[j]);
        int s1 = __builtin_nontemporal_load(&sidx[j + 1]);
        int s2 = __builtin_nontemporal_load(&sidx[j + 2]);
        int s3 = __builtin_nontemporal_load(&sidx[j + 3]);
        uint4 v0 = *(const uint4*)(M + (size_t)s0 * 64 + q * 8);
        uint4 v1 = *(const uint4*)(M + (size_t)s1 * 64 + q * 8);
        uint4 v2 = *(const uint4*)(M + (size_t)s2 * 64 + q * 8);
        uint4 v3 = *(const uint4*)(M + (size_t)s3 * 64 + q * 8);
        float f0[8], f1[8], f2[8], f3[8];
        unpack8(v0, f0); unpack8(v1, f1); unpack8(v2, f2); unpack8(v3, f3);
#pragma unroll
        for (int k = 0; k < 8; ++k)
            acc[k] += (f0[k] + f1[k]) + (f2[k] + f3[k]);
    }
    for (; j < end; ++j) {
        int s = __builtin_nontemporal_load(&sidx[j]);
        uint4 v = *(const uint4*)(M + (size_t)s * 64 + q * 8);
        float f[8];
        unpack8(v, f);
#pragma unroll
        for (int k = 0; k < 8; ++k) acc[k] += f[k];
    }
    float sc = dinv[d];
    float4 b0 = *(const float4*)&b3[q * 8];
    float4 b1 = *(const float4*)&b3[q * 8 + 4];
    float4 r0, r1;
    r0.x = acc[0] * sc + b0.x; r0.y = acc[1] * sc + b0.y;
    r0.z = acc[2] * sc + b0.z; r0.w = acc[3] * sc + b0.w;
    r1.x = acc[4] * sc + b1.x; r1.y = acc[5] * sc + b1.y;
    r1.z = acc[6] * sc + b1.z; r1.w = acc[7] * sc + b1.w;
    float* o = out + (size_t)d * 40 + q * 8;
    nt_store16f(o, r0);
    nt_store16f(o + 4, r1);
}

// ---------------- launch ----------------

extern "C" void kernel_launch(void* const* d_in, const int* in_sizes, int n_in,
                              void* d_out, int out_size, void* d_ws, size_t ws_size,
                              hipStream_t stream) {
    const float* x  = (const float*)d_in[0];
    const int*   ei = (const int*)d_in[1];
    const float* W1 = (const float*)d_in[2];
    const float* g1 = (const float*)d_in[4];
    const float* be1= (const float*)d_in[5];
    const float* W2 = (const float*)d_in[6];
    const float* g2 = (const float*)d_in[8];
    const float* be2= (const float*)d_in[9];
    const float* W3 = (const float*)d_in[10];
    const float* b3 = (const float*)d_in[11];

    const int N = in_sizes[0] / 128;
    const int E = in_sizes[1] / 2;
    const int NB = (N + 255) / 256;
    const int RS = (N + 7) / 8;
    const int EB8 = 8 * ((E + 255) / 256);

    __half* M    = (__half*)d_ws;                 // [4][N][32] stripes
    __half* Hb   = M + (size_t)N * 128;           // [4][N][32] stripes
    __half* t3   = Hb + (size_t)N * 128;          // N*64 (row-major, padded)
    __half* Wt1  = t3 + (size_t)N * 64;           // 128*128
    __half* Wt2  = Wt1 + 128 * 128;
    __half* Wt3  = Wt2 + 128 * 128;               // 48*128
    float* dinv    = (float*)(Wt3 + 48 * 128);
    int*   deg     = (int*)(dinv + N);            // N  (zero block start)
    float* sumsA   = (float*)(deg + N);           // 32*128
    float* sumsqA  = sumsA + 32 * 128;
    float* sumsB   = sumsqA + 32 * 128;
    float* sumsqB  = sumsB + 32 * 128;
    int*   row_ptr = (int*)(sumsqB + 32 * 128);   // N+1
    int*   cursor  = row_ptr + N + 1;             // N
    unsigned short* sidx = (unsigned short*)(cursor + N);  // E
    unsigned short* e16  = sidx + E;              // 2E: dst16 then src16
    int*   bsum    = (int*)(e16 + 2 * E);         // 256
    float* out     = (float*)d_out;

    const unsigned short* dst16 = e16;
    const unsigned short* src16 = e16 + E;

    const int GB = (N + 127) / 128;
    const int ZN = N + 4 * 32 * 128;
    const int SETUP_TOT = 2 * 128 * 128 + 48 * 128 + ZN + 2 * E;
    const int NB64 = (N + 63) / 64;
    const int AGG_GRID = 8 * ((NB64 + 1) / 2);

    // ---- setup (pack W + zero + pack edges) + CSR build ----
    k_setup<<<(SETUP_TOT + 255) / 256, 256, 0, stream>>>(W1, W2, W3, Wt1, Wt2, Wt3,
                                                         deg, ZN, ei, e16, E);
    k_deg_xcd<<<EB8, 256, 0, stream>>>(dst16, deg, E, RS);
    k_chunkscan<<<1, 256, 0, stream>>>(deg, bsum, N);
    k_scanchunk<<<NB, 256, 0, stream>>>(deg, bsum, row_ptr, cursor, dinv, N, E);
    k_place_xcd<<<EB8, 256, 0, stream>>>(src16, dst16, cursor, sidx, E, RS);

    // ---- layer 1: x @ W1 -> M stripes; agg -> Hb stripes + statsA ----
    k_gemm_mfma<4, 128, 128, 0, 2, 0, 1><<<GB * 2, 256, 0, stream>>>(
        x, Wt1, nullptr, nullptr, nullptr, nullptr, dinv, M, N);
    k_agg32_stats<<<AGG_GRID, 256, 0, stream>>>(M, row_ptr, sidx, dinv, Hb, sumsA, sumsqA, N);

    // ---- layer 2: bn1(Hb) @ W2 -> M stripes; agg -> Hb stripes + statsB ----
    k_gemm_mfma<4, 128, 128, 1, 2, 1, 1><<<GB * 2, 256, 0, stream>>>(
        Hb, Wt2, sumsA, sumsqA, g1, be1, dinv, M, N);
    k_agg32_stats<<<AGG_GRID, 256, 0, stream>>>(M, row_ptr, sidx, dinv, Hb, sumsB, sumsqB, N);

    // ---- layer 3: bn2(Hb) @ W3 -> t3 (row-major 64); agg40 -> out ----
    k_gemm_mfma<3, 64, 40, 1, 1, 1, 0><<<GB, 256, 0, stream>>>(
        Hb, Wt3, sumsB, sumsqB, g2, be2, dinv, t3, N);
    k_agg40_f16<<<(N * 5 + 255) / 256, 256, 0, stream>>>(t3, row_ptr, sidx, dinv, b3, out, N);
}

// Round 14
// 221.045 us; speedup vs baseline: 1.1241x; 1.1241x over previous
//
#include <hip/hip_runtime.h>
#include <hip/hip_fp16.h>

typedef _Float16 half8 __attribute__((ext_vector_type(8)));
typedef float floatx4 __attribute__((ext_vector_type(4)));

// ---------------- helpers ----------------

__device__ __forceinline__ void unpack8(uint4 v, float* f) {
    const __half2* hp = (const __half2*)&v;
    float2 a = __half22float2(hp[0]);
    float2 b = __half22float2(hp[1]);
    float2 c = __half22float2(hp[2]);
    float2 d = __half22float2(hp[3]);
    f[0] = a.x; f[1] = a.y; f[2] = b.x; f[3] = b.y;
    f[4] = c.x; f[5] = c.y; f[6] = d.x; f[7] = d.y;
}

__device__ __forceinline__ uint4 pack8(const float* f) {
    __half2 h0 = __floats2half2_rn(f[0], f[1]);
    __half2 h1 = __floats2half2_rn(f[2], f[3]);
    __half2 h2 = __floats2half2_rn(f[4], f[5]);
    __half2 h3 = __floats2half2_rn(f[6], f[7]);
    uint4 v;
    v.x = *(const unsigned int*)&h0;
    v.y = *(const unsigned int*)&h1;
    v.z = *(const unsigned int*)&h2;
    v.w = *(const unsigned int*)&h3;
    return v;
}

// ---------------- setup: W pack + zero + edge uint16 pack (fused) ----------------

__global__ void k_setup(const float* __restrict__ W1, const float* __restrict__ W2,
                        const float* __restrict__ W3, __half* __restrict__ Wt1,
                        __half* __restrict__ Wt2, __half* __restrict__ Wt3,
                        int* __restrict__ zp, int zn,
                        const int* __restrict__ ei, unsigned short* __restrict__ e16,
                        int E) {
    const int PW = 2 * 128 * 128 + 48 * 128;
    int i = blockIdx.x * 256 + threadIdx.x;
    if (i < 128 * 128) {
        int n = i >> 7, k = i & 127;
        Wt1[i] = __float2half(W1[(size_t)k * 128 + n]);
    } else if (i < 2 * 128 * 128) {
        int j = i - 128 * 128;
        int n = j >> 7, k = j & 127;
        Wt2[j] = __float2half(W2[(size_t)k * 128 + n]);
    } else if (i < PW) {
        int j = i - 2 * 128 * 128;
        int n = j >> 7, k = j & 127;
        Wt3[j] = (n < 40) ? __float2half(W3[(size_t)k * 40 + n]) : __half(0.f);
    } else if (i < PW + zn) {
        zp[i - PW] = 0;
    } else {
        int j = i - PW - zn;
        if (j < E) e16[j] = (unsigned short)ei[E + j];            // dst16
        else if (j < 2 * E) e16[j] = (unsigned short)ei[j - E];   // src16
    }
}

// ---------------- CSR build (counting sort, XCD-range-partitioned, uint16) ----------------

__global__ void k_deg_xcd(const unsigned short* __restrict__ dst, int* __restrict__ deg,
                          int E, int rs) {
    int lo = (blockIdx.x & 7) * rs;
    int i = (blockIdx.x >> 3) * 256 + threadIdx.x;
    if (i < E) {
        int d = dst[i];
        if (d >= lo && d < lo + rs) atomicAdd(&deg[d], 1);
    }
}

__global__ void k_place_xcd(const unsigned short* __restrict__ src,
                            const unsigned short* __restrict__ dst,
                            int* __restrict__ cursor, unsigned short* __restrict__ sidx,
                            int E, int rs) {
    int lo = (blockIdx.x & 7) * rs;
    int i = (blockIdx.x >> 3) * 256 + threadIdx.x;
    if (i < E) {
        int d = dst[i];
        if (d >= lo && d < lo + rs) {
            int pos = atomicAdd(&cursor[d], 1);
            sidx[pos] = src[i];
        }
    }
}

__global__ __launch_bounds__(256) void k_chunkscan(const int* __restrict__ deg,
                                                   int* __restrict__ bsum, int n) {
    __shared__ int ls[256];
    int t = threadIdx.x;
    int s = 0;
    int base = t * 256;
    for (int k = 0; k < 256; ++k) {
        int idx = base + k;
        if (idx < n) s += deg[idx];
    }
    ls[t] = s;
    __syncthreads();
    for (int off = 1; off < 256; off <<= 1) {
        int v = t >= off ? ls[t - off] : 0;
        __syncthreads();
        ls[t] += v;
        __syncthreads();
    }
    bsum[t] = ls[t] - s;  // exclusive
}

__global__ void k_scanchunk(const int* __restrict__ cnt, const int* __restrict__ bsum,
                            int* __restrict__ row_ptr, int* __restrict__ cursor,
                            float* __restrict__ dinv, int n, int E) {
    __shared__ int ls[256];
    int i = blockIdx.x * 256 + threadIdx.x;
    int v = i < n ? cnt[i] : 0;
    ls[threadIdx.x] = v;
    __syncthreads();
    for (int off = 1; off < 256; off <<= 1) {
        int t = threadIdx.x >= off ? ls[threadIdx.x - off] : 0;
        __syncthreads();
        ls[threadIdx.x] += t;
        __syncthreads();
    }
    if (i < n) {
        int ex = ls[threadIdx.x] - v + bsum[blockIdx.x];
        row_ptr[i] = ex;
        cursor[i] = ex;
        dinv[i] = v > 0 ? rsqrtf((float)v) : 0.f;
    }
    if (i == n - 1) row_ptr[n] = E;
}

// ---------------- MFMA GEMM v4 (stripe-aware) ----------------
// Intermediate matrices are stored as 4 column stripes [4][N][32] fp16 so that
// the aggregation's gather table per stripe (3.2 MB) fits one XCD's 4 MiB L2.
// ASTRIPE: A fragments read from stripe layout (granularity matches exactly).
// CSTRIPE: C written to stripe layout (fully coalesced per wave).
// AMODE 0: A fp32 row-major. AMODE 1: A fp16, a=relu(a*scale+shift) (BN fused).

template <int CT, int STRIDE, int VALID, int AMODE, int CSPLIT, int ASTRIPE, int CSTRIPE>
__global__ __launch_bounds__(256) void k_gemm_mfma(const void* __restrict__ Ap,
                                                   const __half* __restrict__ Wt,
                                                   const float* __restrict__ sums32,
                                                   const float* __restrict__ sumsq32,
                                                   const float* __restrict__ g,
                                                   const float* __restrict__ beta,
                                                   const float* __restrict__ dinv,
                                                   __half* __restrict__ C, int nrows) {
    constexpr int CW = CT * 16;
    __shared__ char lw[CT * 16 * 256];
    __shared__ float lsc[128], lsh[128];
    const int rowblk = (CSPLIT == 2) ? (blockIdx.x >> 1) : blockIdx.x;
    const int colblk = (CSPLIT == 2) ? (blockIdx.x & 1) : 0;

    const int lane = threadIdx.x & 63;
    const int wid = threadIdx.x >> 6;
    const int l15 = lane & 15;
    const int lg = lane >> 4;
    const int rowbase = rowblk * 128 + wid * 32;

    // ---- phase 0: issue raw A loads (latency hides under W staging) ----
    uint4 raw16[2][4];
    float4 raw32[2][4][2];
#pragma unroll
    for (int r = 0; r < 2; ++r) {
        int row = rowbase + r * 16 + l15;
        bool ok = row < nrows;
#pragma unroll
        for (int kk = 0; kk < 4; ++kk) {
            const int c0 = kk * 32 + lg * 8;
            if (AMODE == 0) {
                const float* a = (const float*)Ap + (size_t)row * 128 + c0;
                raw32[r][kk][0] = ok ? *(const float4*)a : make_float4(0.f, 0.f, 0.f, 0.f);
                raw32[r][kk][1] = ok ? *(const float4*)(a + 4) : make_float4(0.f, 0.f, 0.f, 0.f);
            } else if (ASTRIPE) {
                const __half* a = (const __half*)Ap + ((size_t)kk * nrows + row) * 32 + lg * 8;
                raw16[r][kk] = ok ? *(const uint4*)a : make_uint4(0, 0, 0, 0);
            } else {
                raw16[r][kk] = ok ? *(const uint4*)((const __half*)Ap + (size_t)row * 128 + c0)
                                  : make_uint4(0, 0, 0, 0);
            }
        }
    }

    // ---- phase 1: W stage + BN coeffs ----
    const int nu4 = CT * 16 * 16;
    for (int i = threadIdx.x; i < nu4; i += 256) {
        int row = i >> 4, k8 = i & 15;
        uint4 v = ((const uint4*)Wt)[(colblk * CW + row) * 16 + k8];
        *(uint4*)(lw + ((row * 256 + k8 * 16) ^ ((row & 7) << 4))) = v;
    }
    if (AMODE == 1 && threadIdx.x < 128) {
        int c = threadIdx.x;
        float s = 0.f, q = 0.f;
        for (int k2 = 0; k2 < 32; ++k2) {
            s += sums32[k2 * 128 + c];
            q += sumsq32[k2 * 128 + c];
        }
        float inv_n = 1.f / (float)nrows;
        float mu = s * inv_n;
        float var = q * inv_n - mu * mu;
        float rs = rsqrtf(var + 1e-5f);
        float sc = rs * g[c];
        lsc[c] = sc;
        lsh[c] = beta[c] - mu * sc;
    }
    __syncthreads();

    // ---- phase 2: convert/BN-apply A fragments ----
    half8 a2[2][4];
#pragma unroll
    for (int r = 0; r < 2; ++r) {
#pragma unroll
        for (int kk = 0; kk < 4; ++kk) {
            const int c0 = kk * 32 + lg * 8;
            half8 h;
            if (AMODE == 0) {
                float4 v0 = raw32[r][kk][0];
                float4 v1 = raw32[r][kk][1];
                h[0] = (_Float16)v0.x; h[1] = (_Float16)v0.y;
                h[2] = (_Float16)v0.z; h[3] = (_Float16)v0.w;
                h[4] = (_Float16)v1.x; h[5] = (_Float16)v1.y;
                h[6] = (_Float16)v1.z; h[7] = (_Float16)v1.w;
            } else {
                float f[8];
                unpack8(raw16[r][kk], f);
                float4 s0 = *(const float4*)&lsc[c0];
                float4 s1 = *(const float4*)&lsc[c0 + 4];
                float4 t0 = *(const float4*)&lsh[c0];
                float4 t1 = *(const float4*)&lsh[c0 + 4];
                h[0] = (_Float16)fmaxf(f[0] * s0.x + t0.x, 0.f);
                h[1] = (_Float16)fmaxf(f[1] * s0.y + t0.y, 0.f);
                h[2] = (_Float16)fmaxf(f[2] * s0.z + t0.z, 0.f);
                h[3] = (_Float16)fmaxf(f[3] * s0.w + t0.w, 0.f);
                h[4] = (_Float16)fmaxf(f[4] * s1.x + t1.x, 0.f);
                h[5] = (_Float16)fmaxf(f[5] * s1.y + t1.y, 0.f);
                h[6] = (_Float16)fmaxf(f[6] * s1.z + t1.z, 0.f);
                h[7] = (_Float16)fmaxf(f[7] * s1.w + t1.w, 0.f);
            }
            a2[r][kk] = h;
        }
    }

    floatx4 acc[2][CT];
#pragma unroll
    for (int r = 0; r < 2; ++r)
#pragma unroll
        for (int c = 0; c < CT; ++c) acc[r][c] = (floatx4){0.f, 0.f, 0.f, 0.f};

#pragma unroll
    for (int kk = 0; kk < 4; ++kk) {
#pragma unroll
        for (int c = 0; c < CT; ++c) {
            int wrow = c * 16 + l15;
            half8 bfrag = *(const half8*)(lw + ((wrow * 256 + kk * 64 + lg * 16) ^ ((wrow & 7) << 4)));
#pragma unroll
            for (int r = 0; r < 2; ++r)
                acc[r][c] = __builtin_amdgcn_mfma_f32_16x16x32_f16(a2[r][kk], bfrag, acc[r][c], 0, 0, 0);
        }
    }

    // ---- epilogue: LDS transpose [128][CW], coalesced stores ----
    __syncthreads();
    __half* ct = (__half*)lw;
#pragma unroll
    for (int r = 0; r < 2; ++r) {
        int lr0 = wid * 32 + r * 16 + lg * 4;
        float d4[4];
#pragma unroll
        for (int j = 0; j < 4; ++j) {
            int row = rowblk * 128 + lr0 + j;
            d4[j] = row < nrows ? dinv[row] : 0.f;
        }
#pragma unroll
        for (int c = 0; c < CT; ++c) {
            int col = c * 16 + l15;
#pragma unroll
            for (int j = 0; j < 4; ++j) {
                int lrow = lr0 + j;
                int cc = (CW == 64) ? (col ^ (((lrow >> 2) & 1) << 5)) : col;
                ct[lrow * CW + cc] = __float2half(acc[r][c][j] * d4[j]);
            }
        }
    }
    __syncthreads();
    constexpr int U = CW / 8;
    for (int i = threadIdx.x; i < 128 * U; i += 256) {
        int lrow = i / U, u = i % U;
        int row = rowblk * 128 + lrow;
        int col0 = u * 8;
        int g2 = colblk * CW + col0;
        if (row < nrows && (CSTRIPE || col0 < VALID)) {
            int cc = (CW == 64) ? (col0 ^ (((lrow >> 2) & 1) << 5)) : col0;
            uint4 v = *(const uint4*)&ct[lrow * CW + cc];
            if (CSTRIPE)
                *(uint4*)(&C[((size_t)(g2 >> 5) * nrows + row) * 32 + (g2 & 31)]) = v;
            else
                *(uint4*)(&C[(size_t)row * STRIDE + g2]) = v;
        }
    }
}

// ---------------- stripe aggregation + fused BN stats ----------------
// Pass p (cols 32p..32p+32) gathers from stripe M4[p] (3.2 MB, L2-resident),
// pinned to XCDs {2p,2p+1} via pass=(blockIdx>>1)&3 (blockIdx%8->XCD heuristic).
// 4 lanes/node (uint4 each), 64 nodes/block.

__global__ __launch_bounds__(256) void k_agg32_stats(const __half* __restrict__ M4,
                                                     const int* __restrict__ rp,
                                                     const unsigned short* __restrict__ sidx,
                                                     const float* __restrict__ dinv,
                                                     __half* __restrict__ H4,
                                                     float* __restrict__ sums32,
                                                     float* __restrict__ sumsq32, int n) {
    int b = blockIdx.x;
    int pass = (b >> 1) & 3;
    int nodeblk = (b >> 3) * 2 + (b & 1);
    int tid = threadIdx.x;
    int d = nodeblk * 64 + (tid >> 2);
    int lane4 = tid & 3;
    const __half* Mp = M4 + (size_t)pass * n * 32;

    float acc[8] = {0.f, 0.f, 0.f, 0.f, 0.f, 0.f, 0.f, 0.f};
    if (d < n) {
        int beg = rp[d], end = rp[d + 1];
        int j = beg;
        for (; j + 4 <= end; j += 4) {
            uint4 v0 = *(const uint4*)(Mp + (size_t)sidx[j]     * 32 + lane4 * 8);
            uint4 v1 = *(const uint4*)(Mp + (size_t)sidx[j + 1] * 32 + lane4 * 8);
            uint4 v2 = *(const uint4*)(Mp + (size_t)sidx[j + 2] * 32 + lane4 * 8);
            uint4 v3 = *(const uint4*)(Mp + (size_t)sidx[j + 3] * 32 + lane4 * 8);
            float f0[8], f1[8], f2[8], f3[8];
            unpack8(v0, f0); unpack8(v1, f1); unpack8(v2, f2); unpack8(v3, f3);
#pragma unroll
            for (int i = 0; i < 8; ++i)
                acc[i] += (f0[i] + f1[i]) + (f2[i] + f3[i]);
        }
        for (; j < end; ++j) {
            uint4 v = *(const uint4*)(Mp + (size_t)sidx[j] * 32 + lane4 * 8);
            float f[8];
            unpack8(v, f);
#pragma unroll
            for (int i = 0; i < 8; ++i) acc[i] += f[i];
        }
        float sc = dinv[d];
#pragma unroll
        for (int i = 0; i < 8; ++i) acc[i] *= sc;
        *(uint4*)(H4 + (size_t)pass * n * 32 + (size_t)d * 32 + lane4 * 8) = pack8(acc);
    }

    // per-pass column stats (cols pass*32 + lane4*8 + [0,8))
    float sq[8];
#pragma unroll
    for (int i = 0; i < 8; ++i) sq[i] = acc[i] * acc[i];
#pragma unroll
    for (int m = 4; m <= 32; m <<= 1) {
#pragma unroll
        for (int i = 0; i < 8; ++i) {
            acc[i] += __shfl_xor(acc[i], m);
            sq[i]  += __shfl_xor(sq[i], m);
        }
    }
    __shared__ float lsw[2][4][4][8];  // 1 KB
    int wid = tid >> 6, wl = tid & 63;
    if (wl < 4) {
#pragma unroll
        for (int i = 0; i < 8; ++i) {
            lsw[0][wid][wl][i] = acc[i];
            lsw[1][wid][wl][i] = sq[i];
        }
    }
    __syncthreads();
    if (tid < 32) {
        int lc = tid >> 3, e = tid & 7;
        float ss = 0.f, qq = 0.f;
#pragma unroll
        for (int w = 0; w < 4; ++w) {
            ss += lsw[0][w][lc][e];
            qq += lsw[1][w][lc][e];
        }
        int sh = (b & 31) * 128;
        int c = pass * 32 + tid;
        atomicAdd(&sums32[sh + c], ss);
        atomicAdd(&sumsq32[sh + c], qq);
    }
}

// ---------------- layer-3 aggregation (t3 row stride 64) ----------------

__global__ void k_agg40_f16(const __half* __restrict__ M,
                            const int* __restrict__ rp,
                            const unsigned short* __restrict__ sidx,
                            const float* __restrict__ dinv,
                            const float* __restrict__ b3,
                            float* __restrict__ out, int n) {
    int i = blockIdx.x * 256 + threadIdx.x;
    if (i >= n * 5) return;
    int d = i / 5, q = i % 5;
    int beg = rp[d], end = rp[d + 1];
    float acc[8] = {0.f, 0.f, 0.f, 0.f, 0.f, 0.f, 0.f, 0.f};
    int j = beg;
    for (; j + 4 <= end; j += 4) {
        uint4 v0 = *(const uint4*)(M + (size_t)sidx[j] * 64 + q * 8);
        uint4 v1 = *(const uint4*)(M + (size_t)sidx[j + 1] * 64 + q * 8);
        uint4 v2 = *(const uint4*)(M + (size_t)sidx[j + 2] * 64 + q * 8);
        uint4 v3 = *(const uint4*)(M + (size_t)sidx[j + 3] * 64 + q * 8);
        float f0[8], f1[8], f2[8], f3[8];
        unpack8(v0, f0); unpack8(v1, f1); unpack8(v2, f2); unpack8(v3, f3);
#pragma unroll
        for (int k = 0; k < 8; ++k)
            acc[k] += (f0[k] + f1[k]) + (f2[k] + f3[k]);
    }
    for (; j < end; ++j) {
        uint4 v = *(const uint4*)(M + (size_t)sidx[j] * 64 + q * 8);
        float f[8];
        unpack8(v, f);
#pragma unroll
        for (int k = 0; k < 8; ++k) acc[k] += f[k];
    }
    float sc = dinv[d];
    float4 b0 = *(const float4*)&b3[q * 8];
    float4 b1 = *(const float4*)&b3[q * 8 + 4];
    float4 r0, r1;
    r0.x = acc[0] * sc + b0.x; r0.y = acc[1] * sc + b0.y;
    r0.z = acc[2] * sc + b0.z; r0.w = acc[3] * sc + b0.w;
    r1.x = acc[4] * sc + b1.x; r1.y = acc[5] * sc + b1.y;
    r1.z = acc[6] * sc + b1.z; r1.w = acc[7] * sc + b1.w;
    float* o = out + (size_t)d * 40 + q * 8;
    *(float4*)o = r0;
    *(float4*)(o + 4) = r1;
}

// ---------------- launch ----------------

extern "C" void kernel_launch(void* const* d_in, const int* in_sizes, int n_in,
                              void* d_out, int out_size, void* d_ws, size_t ws_size,
                              hipStream_t stream) {
    const float* x  = (const float*)d_in[0];
    const int*   ei = (const int*)d_in[1];
    const float* W1 = (const float*)d_in[2];
    const float* g1 = (const float*)d_in[4];
    const float* be1= (const float*)d_in[5];
    const float* W2 = (const float*)d_in[6];
    const float* g2 = (const float*)d_in[8];
    const float* be2= (const float*)d_in[9];
    const float* W3 = (const float*)d_in[10];
    const float* b3 = (const float*)d_in[11];

    const int N = in_sizes[0] / 128;
    const int E = in_sizes[1] / 2;
    const int NB = (N + 255) / 256;
    const int RS = (N + 7) / 8;
    const int EB8 = 8 * ((E + 255) / 256);

    __half* M    = (__half*)d_ws;                 // [4][N][32] stripes
    __half* Hb   = M + (size_t)N * 128;           // [4][N][32] stripes
    __half* t3   = Hb + (size_t)N * 128;          // N*64 (row-major, padded)
    __half* Wt1  = t3 + (size_t)N * 64;           // 128*128
    __half* Wt2  = Wt1 + 128 * 128;
    __half* Wt3  = Wt2 + 128 * 128;               // 48*128
    float* dinv    = (float*)(Wt3 + 48 * 128);
    int*   deg     = (int*)(dinv + N);            // N  (zero block start)
    float* sumsA   = (float*)(deg + N);           // 32*128
    float* sumsqA  = sumsA + 32 * 128;
    float* sumsB   = sumsqA + 32 * 128;
    float* sumsqB  = sumsB + 32 * 128;
    int*   row_ptr = (int*)(sumsqB + 32 * 128);   // N+1
    int*   cursor  = row_ptr + N + 1;             // N
    unsigned short* sidx = (unsigned short*)(cursor + N);  // E
    unsigned short* e16  = sidx + E;              // 2E: dst16 then src16
    int*   bsum    = (int*)(e16 + 2 * E);         // 256
    float* out     = (float*)d_out;

    const unsigned short* dst16 = e16;
    const unsigned short* src16 = e16 + E;

    const int GB = (N + 127) / 128;
    const int ZN = N + 4 * 32 * 128;
    const int SETUP_TOT = 2 * 128 * 128 + 48 * 128 + ZN + 2 * E;
    const int NB64 = (N + 63) / 64;
    const int AGG_GRID = 8 * ((NB64 + 1) / 2);

    // ---- setup (pack W + zero + pack edges) + CSR build ----
    k_setup<<<(SETUP_TOT + 255) / 256, 256, 0, stream>>>(W1, W2, W3, Wt1, Wt2, Wt3,
                                                         deg, ZN, ei, e16, E);
    k_deg_xcd<<<EB8, 256, 0, stream>>>(dst16, deg, E, RS);
    k_chunkscan<<<1, 256, 0, stream>>>(deg, bsum, N);
    k_scanchunk<<<NB, 256, 0, stream>>>(deg, bsum, row_ptr, cursor, dinv, N, E);
    k_place_xcd<<<EB8, 256, 0, stream>>>(src16, dst16, cursor, sidx, E, RS);

    // ---- layer 1: x @ W1 -> M stripes; agg -> Hb stripes + statsA ----
    k_gemm_mfma<4, 128, 128, 0, 2, 0, 1><<<GB * 2, 256, 0, stream>>>(
        x, Wt1, nullptr, nullptr, nullptr, nullptr, dinv, M, N);
    k_agg32_stats<<<AGG_GRID, 256, 0, stream>>>(M, row_ptr, sidx, dinv, Hb, sumsA, sumsqA, N);

    // ---- layer 2: bn1(Hb) @ W2 -> M stripes; agg -> Hb stripes + statsB ----
    k_gemm_mfma<4, 128, 128, 1, 2, 1, 1><<<GB * 2, 256, 0, stream>>>(
        Hb, Wt2, sumsA, sumsqA, g1, be1, dinv, M, N);
    k_agg32_stats<<<AGG_GRID, 256, 0, stream>>>(M, row_ptr, sidx, dinv, Hb, sumsB, sumsqB, N);

    // ---- layer 3: bn2(Hb) @ W3 -> t3 (row-major 64); agg40 -> out ----
    k_gemm_mfma<3, 64, 40, 1, 1, 1, 0><<<GB, 256, 0, stream>>>(
        Hb, Wt3, sumsB, sumsqB, g2, be2, dinv, t3, N);
    k_agg40_f16<<<(N * 5 + 255) / 256, 256, 0, stream>>>(t3, row_ptr, sidx, dinv, b3, out, N);
}